// Round 11
// baseline (634.245 us; speedup 1.0000x reference)
//
#include <hip/hip_runtime.h>

#define OUTD 66
#define INW  78
#define FH   2048
#define LEN  64

typedef short bf16x8 __attribute__((ext_vector_type(8)));
typedef float f32x4  __attribute__((ext_vector_type(4)));
typedef unsigned int u32x4 __attribute__((ext_vector_type(4)));

__device__ __forceinline__ float bf2f(unsigned short u) {
  union { unsigned int i; float f; } v; v.i = ((unsigned int)u) << 16; return v.f;
}
__device__ __forceinline__ unsigned short f2bf(float f) {
  union { float f; unsigned int i; } v; v.f = f;
  unsigned int u = v.i;
  return (unsigned short)((u + 0x7fffu + ((u >> 16) & 1u)) >> 16);
}
__device__ __forceinline__ float sigm(float x) { return 1.f / (1.f + __expf(-x)); }
__device__ __forceinline__ float tanh_f(float x) { return 2.f / (1.f + __expf(-2.f * x)) - 1.f; }

// Returning atomic add executed at XCD-local L2 (validated r4/r6 fast path).
__device__ __forceinline__ unsigned int atom_add_ret(unsigned int* p, unsigned int d) {
  unsigned int r;
  asm volatile("global_atomic_add %0, %1, %2, off sc0\n\ts_waitcnt vmcnt(0)"
               : "=&v"(r) : "v"(p), "v"(d) : "memory");
  return r;
}

// ---- initA (all inputs FLOAT32):
//  blocks 0..255 : Weff(bf16) = W_hh + W_ihA·W_fc fold, bias_eff(f32), zero flags/flagsL
//  blocks 256..511: h0 -> hbuf[0] (bf16, CHUNK layout), c0 (f32); block 256 converts W_fc -> Wfc16
// hbuf chunk layout: [parity][mt(16)][jt(32)][r(32)][c(16)] bf16 -> producer tile = 1KB contiguous.
__global__ __launch_bounds__(256) void k_initA(
    const float* __restrict__ W_hh, const float* __restrict__ W_ih,
    const float* __restrict__ W_fc, const float* __restrict__ b_ih,
    const float* __restrict__ b_hh, const float* __restrict__ b_fc,
    const float* __restrict__ inp, const float* __restrict__ W_inh,
    const float* __restrict__ b_inh, const float* __restrict__ W_inc,
    const float* __restrict__ b_inc,
    unsigned short* __restrict__ Weff, float* __restrict__ bias_eff,
    unsigned short* __restrict__ hbuf, float* __restrict__ c0,
    unsigned short* __restrict__ Wfc16, unsigned int* __restrict__ flags,
    unsigned int* __restrict__ flagsL)
{
  int tid = threadIdx.x, bid = blockIdx.x;
  if (bid < 256) {
    int nb = bid;
    int k = tid * 2;
    float acc[8][2];
    #pragma unroll
    for (int r = 0; r < 8; ++r) {
      int n = nb * 8 + r;
      acc[r][0] = W_hh[n * 512 + k];
      acc[r][1] = W_hh[n * 512 + k + 1];
    }
    for (int m = 0; m < OUTD; ++m) {
      float w0 = W_fc[m * 512 + k];
      float w1 = W_fc[m * 512 + k + 1];
      #pragma unroll
      for (int r = 0; r < 8; ++r) {
        float wih = W_ih[(nb * 8 + r) * INW + m];
        acc[r][0] += wih * w0;
        acc[r][1] += wih * w1;
      }
    }
    #pragma unroll
    for (int r = 0; r < 8; ++r) {
      int n = nb * 8 + r;
      unsigned int pack = (unsigned int)f2bf(acc[r][0]) | ((unsigned int)f2bf(acc[r][1]) << 16);
      *(unsigned int*)(Weff + n * 512 + k) = pack;
    }
    if (tid < 8) {
      int n = nb * 8 + tid;
      float a = b_ih[n] + b_hh[n];
      for (int m = 0; m < OUTD; ++m) a += b_fc[m] * W_ih[n * INW + m];
      bias_eff[n] = a;
    }
    if (nb == 0) {
      for (int i = tid; i < 512 * 16; i += 256) flags[i] = 0;
      for (int i = tid; i < 256 * 16; i += 256) flagsL[i] = 0;
    }
  } else {
    int nb = bid - 256;
    for (int r = 0; r < 2; ++r) {
      int b = nb * 2 + r;
      for (int half = 0; half < 2; ++half) {
        int c = tid + half * 256;
        float ha = b_inh[c], ca = b_inc[c];
        for (int m = 0; m < OUTD; ++m) {
          float f = inp[b * OUTD + m];
          ha += f * W_inh[c * OUTD + m];
          ca += f * W_inc[c * OUTD + m];
        }
        // chunk layout write: [mt=b>>5][jt=c>>4][r=b&31][c&15]
        hbuf[((b >> 5) * 32 + (c >> 4)) * 512 + (b & 31) * 16 + (c & 15)] = f2bf(ha);
        c0[b * 512 + c] = ca;
      }
    }
    if (nb == 0) {
      for (int i = tid; i < OUTD * 512; i += 256) Wfc16[i] = f2bf(W_fc[i]);
    }
  }
}

// ---- init2a: d0[b][m] = frame0 - (h0(bf16, chunk layout) @ W_fc^T + b_fc)
__global__ __launch_bounds__(128) void k_init2a(
    const float* __restrict__ inp, const unsigned short* __restrict__ hbuf,
    const float* __restrict__ W_fc, const float* __restrict__ b_fc,
    float* __restrict__ d0)
{
  int b = blockIdx.x, m = threadIdx.x;
  if (m >= OUTD) return;
  const unsigned short* hb = hbuf + (b >> 5) * 16384 + (b & 31) * 16;
  const float* wrow = W_fc + m * 512;
  float acc = 0.f;
  for (int k = 0; k < 512; ++k)
    acc += bf2f(hb[(k >> 4) * 512 + (k & 15)]) * wrow[k];
  d0[b * OUTD + m] = inp[b * OUTD + m] - (acc + b_fc[m]);
}

// ---- init2b: corr0[b][n] = d0[b] @ W_ihA[n]^T
__global__ __launch_bounds__(256) void k_init2b(
    const float* __restrict__ d0, const float* __restrict__ W_ih,
    float* __restrict__ corr0)
{
  __shared__ float ds[4][OUTD];
  int tid = threadIdx.x, b0 = blockIdx.x * 4;
  for (int i = tid; i < 4 * OUTD; i += 256) ds[i / OUTD][i % OUTD] = d0[b0 * OUTD + i];
  __syncthreads();
  for (int n = tid; n < FH; n += 256) {
    float a0 = 0, a1 = 0, a2 = 0, a3 = 0;
    const float* wr = W_ih + n * INW;
    for (int m = 0; m < OUTD; ++m) {
      float w = wr[m];
      a0 += ds[0][m] * w; a1 += ds[1][m] * w; a2 += ds[2][m] * w; a3 += ds[3][m] * w;
    }
    corr0[(b0 + 0) * FH + n] = a0;
    corr0[(b0 + 1) * FH + n] = a1;
    corr0[(b0 + 2) * FH + n] = a2;
    corr0[(b0 + 3) * FH + n] = a3;
  }
}

// ---- main persistent LSTM kernel (r11 = r6 champion + publish-chain deltas).
// Base = r6 exactly (512 blocks, 32 rows, 2/CU, swizzle-8, GO broadcast, carried fc).
// Delta A (fan-in tree): publishers atom_add one of 4 sub-counters (8 each, separate
//   64B lines); sub-completer (old==7) bumps the master (old==3 -> GO). Worst-case
//   same-word RMW queue drops 31 -> 7+3.
// Delta B (out-ack off the gated drain, r9-bug-safe): out stores issue AFTER the
//   h-store; fc-waves drain with vmcnt(4) -- the 4 outs are the youngest vmem ops,
//   so <=4 outstanding proves h (older) is acked; out acks retire during GO-wait/E.
//   E's buffer_inv+vmcnt(0) runs ONLY on waves 2-3 (for fc-blocks they stage all 32
//   chunks; waves 0-1 run fc concurrently and never wait vmem).
// flagsL layout per group (base mt*256 words, 1KB): [0..3] master ring,
//   [16*(1+sub)+slot] sub rings (4 lines), [80..83] GO ring. Monotone GO, ring-of-4,
//   GO-writer re-zeros slot s+3 (master + 4 subs). Bounded spins -> permanent
//   demotion to agent-scope per-producer flags (always dual-published).
__global__ __launch_bounds__(256, 2) void k_main(
    const unsigned short* __restrict__ Weff, const float* __restrict__ bias_eff,
    unsigned short* __restrict__ hbuf, const float* __restrict__ c0,
    const float* __restrict__ corr0, const float* __restrict__ W_ih,
    const int* __restrict__ labels, const unsigned short* __restrict__ Wfc16,
    const float* __restrict__ b_fc, float* __restrict__ out,
    unsigned int* __restrict__ flags, unsigned int* __restrict__ flagsL)
{
  __shared__ __align__(16) unsigned short h_lds[32 * 512];  // 32768 B, XOR-swizzled 16B granules

  int tid = threadIdx.x, bid = blockIdx.x;
  int w = tid >> 6, lane = tid & 63;
  int lc = lane & 15, kg = lane >> 4;
  // flags word layout: [0,4096) step flags (512 producers x stride 8)
  //                    4100 decision word ; [4608, 6656) xmap (512 x stride 4)
  unsigned int* xmap = flags + 4608;
  unsigned int* decp = flags + 4100;

  // ---- publish my XCC_ID (gfx950-verified: learn_hip m09)
  unsigned int xcd;
  asm volatile("s_getreg_b32 %0, hwreg(HW_REG_XCC_ID)" : "=s"(xcd));
  if (tid == 0)
    __hip_atomic_store(&xmap[bid * 4], xcd + 1u, __ATOMIC_RELAXED, __HIP_MEMORY_SCOPE_AGENT);

  // ---- leader (block 0, wave 0) verifies both candidate layouts, publishes decision
  if (bid == 0 && w == 0) {
    int okA = 1, okB = 1;
    #pragma unroll
    for (int i = 0; i < 8; ++i) {
      int b = lane + i * 64;
      unsigned int v, ra, rb;
      const unsigned int* xp = &xmap[b * 4];
      for (;;) { v = __hip_atomic_load(xp, __ATOMIC_RELAXED, __HIP_MEMORY_SCOPE_AGENT);
                 if (v) break; __builtin_amdgcn_s_sleep(1); }
      const unsigned int* pa = &xmap[(b & 15) * 4];
      for (;;) { ra = __hip_atomic_load(pa, __ATOMIC_RELAXED, __HIP_MEMORY_SCOPE_AGENT);
                 if (ra) break; __builtin_amdgcn_s_sleep(1); }
      const unsigned int* pb = &xmap[((b >> 5) << 5) * 4];
      for (;;) { rb = __hip_atomic_load(pb, __ATOMIC_RELAXED, __HIP_MEMORY_SCOPE_AGENT);
                 if (rb) break; __builtin_amdgcn_s_sleep(1); }
      okA &= (v == ra); okB &= (v == rb);
    }
    okA = __all(okA); okB = __all(okB);
    if (lane == 0) {
      unsigned int d = okA ? 1u : (okB ? 2u : 3u);
      __hip_atomic_store(decp, d, __ATOMIC_RELAXED, __HIP_MEMORY_SCOPE_AGENT);
    }
  }
  if (tid == 0) {
    unsigned int dd;
    for (;;) { dd = __hip_atomic_load(decp, __ATOMIC_RELAXED, __HIP_MEMORY_SCOPE_AGENT);
               if (dd) break; __builtin_amdgcn_s_sleep(1); }
    h_lds[0] = (unsigned short)dd;
  }
  __syncthreads();
  unsigned int dmode = h_lds[0];
  __syncthreads();

  int fast, mt, jt;
  if (dmode == 1u)      { fast = 1; mt = bid & 15;  jt = bid >> 4; }
  else if (dmode == 2u) { fast = 1; mt = bid >> 5;  jt = bid & 31; }
  else                  { fast = 0; mt = bid & 15;  jt = bid >> 4; }

  int row0 = mt * 32, j0 = jt * 16;
  int hx0 = (w >> 1) * 8;
  int xloc = lc & 7;
  int G = lc >> 3;                       // 0: holds gates i,g ; 1: holds f,o
  int hcol = j0 + hx0 + xloc;            // global hidden col this lane activates
  int rw0 = (w & 1) * 16;                // wave-local row base (rows 0..31)

  // LDS swizzle precompute (addr_i = P ^ (i<<6)); period-8 (r6-proven)
  int sA = xloc;
  int tA16 = ((kg ^ sA) & 3) << 4;
  int ue64 = ((sA >> 2) & 1) << 6;
  int PA0 = (rw0 + lc) * 1024 + tA16 + ue64;
  int PF  = ((w & 1) * 16 + lc) * 1024 + tA16 + ue64;  // fc rows, waves 0..1

  // ---- Weff B fragments (step-invariant)
  bf16x8 Bfrag[16][2];
  #pragma unroll
  for (int cg = 0; cg < 2; ++cg) {
    int n = (cg * 2 + G) * 512 + hcol;
    const unsigned short* p = Weff + n * 512 + kg * 8;
    #pragma unroll
    for (int i = 0; i < 16; ++i) Bfrag[i][cg] = *(const bf16x8*)(p + i * 32);
  }

  // ---- W_fc B fragments for fused fc (waves 0..1; jt<5 covers out cols 0..79)
  bf16x8 Wf[16];
  float fcb = 0.f;
  int dofcW = (jt < 5) & (w < 2);
  {
    int n = j0 + lc;
    if (dofcW && n < OUTD) {
      const unsigned short* p = Wfc16 + n * 512 + kg * 8;
      #pragma unroll
      for (int i = 0; i < 16; ++i) Wf[i] = *(const bf16x8*)(p + i * 32);
      fcb = b_fc[n];
    } else {
      bf16x8 z8 = {0, 0, 0, 0, 0, 0, 0, 0};
      #pragma unroll
      for (int i = 0; i < 16; ++i) Wf[i] = z8;
    }
  }

  // ---- activation constants (2 h values per lane: rows rw0+kg*4+qsel+{0,1})
  int qsel = G * 2;
  float lt[4][2], creg[2];
  #pragma unroll
  for (int idx = 0; idx < 2; ++idx) {
    int rloc = rw0 + kg * 4 + qsel + idx;
    int grow = row0 + rloc;
    int lab = labels[grow];
    #pragma unroll
    for (int gt = 0; gt < 4; ++gt) {
      int n = gt * 512 + hcol;
      lt[gt][idx] = bias_eff[n] + W_ih[n * INW + OUTD + lab];
    }
    creg[idx] = c0[grow * 512 + hcol];
  }

  const f32x4 z = {0.f, 0.f, 0.f, 0.f};
  unsigned int* myflag = &flags[(mt * 32 + jt) * 8];
  unsigned int* gbase = flagsL + mt * 256;   // 1KB group region (tree + GO)
  int agentMode = !fast;   // wave3 demotion is permanent

  // ---- prologue: stage h_0 (parity 0, chunk layout, contiguous) into LDS
  {
    const unsigned short* hsrc = hbuf + mt * 16384;
    #pragma unroll
    for (int i = 0; i < 8; ++i) {
      int n = tid + i * 256;              // 16B piece index 0..2047
      int c = n >> 6, q = n & 63;
      int r = q >> 1, u = q & 1, g = c * 2 + u;
      *(u32x4*)(h_lds + r * 512 + ((g ^ (r & 7)) << 3)) =
          *(const u32x4*)(hsrc + n * 8);
    }
  }
  __syncthreads();

  f32x4 faP = z; int havP = 0, colP = 0;

  for (int s = 0; s < LEN; ++s) {
    // ---- A: gates = h_s @ Weff (h_s in LDS)
    f32x4 acc00 = z, acc01 = z;
    #pragma unroll
    for (int i = 0; i < 16; ++i) {
      bf16x8 a0 = *(const bf16x8*)((const char*)h_lds + (PA0 ^ (i << 6)));
      acc00 = __builtin_amdgcn_mfma_f32_16x16x32_bf16(a0, Bfrag[i][0], acc00, 0, 0, 0);
      acc01 = __builtin_amdgcn_mfma_f32_16x16x32_bf16(a0, Bfrag[i][1], acc01, 0, 0, 0);
    }

    // exchange missing gates with partner lane (lane^8)
    f32x4 sh00, sh01;
    #pragma unroll
    for (int j = 0; j < 4; ++j) {
      sh00[j] = __shfl_xor(acc00[j], 8);
      sh01[j] = __shfl_xor(acc01[j], 8);
    }

    // activation (2 values per lane)
    unsigned short hval[2];
    #pragma unroll
    for (int idx = 0; idx < 2; ++idx) {
      int qo = qsel + idx;
      float xi = (G ? sh00[qo] : acc00[qo]);
      float xf = (G ? acc00[qo] : sh00[qo]);
      float xg = (G ? sh01[qo] : acc01[qo]);
      float xo = (G ? acc01[qo] : sh01[qo]);
      xi += lt[0][idx]; xf += lt[1][idx]; xg += lt[2][idx]; xo += lt[3][idx];
      if (s == 0) {
        int rloc = rw0 + kg * 4 + qo;
        const float* cr = corr0 + (long)(row0 + rloc) * FH + hcol;
        xi += cr[0]; xf += cr[512]; xg += cr[1024]; xo += cr[1536];
      }
      float cn = sigm(xf) * creg[idx] + sigm(xi) * tanh_f(xg);
      creg[idx] = cn;
      hval[idx] = f2bf(sigm(xo) * tanh_f(cn));
    }

    // ---- store h_{s+1} FIRST (oldest vmem op before the drain)
    {
      unsigned int* hdst32 = (unsigned int*)(hbuf + ((s + 1) & 1) * 262144);
      int base32 = (mt * 32 + jt) * 256;
      int ceL = (hx0 >> 1) + (xloc >> 1);    // local col-pair 0..7
      int odd = xloc & 1;
      unsigned int pkS = 0; int rlS = 0;
      #pragma unroll
      for (int idx = 0; idx < 2; ++idx) {
        unsigned int mine = hval[idx];
        unsigned int part = (unsigned int)__shfl_xor((int)mine, 1);
        unsigned int p = odd ? (part | (mine << 16)) : (mine | (part << 16));
        if (idx == odd) { pkS = p; rlS = rw0 + kg * 4 + qsel + idx; }
      }
      if (fast) {
        hdst32[base32 + rlS * 8 + ceL] = pkS;
      } else {
        __hip_atomic_store(&hdst32[base32 + rlS * 8 + ceL], pkS,
                           __ATOMIC_RELAXED, __HIP_MEMORY_SCOPE_AGENT);
      }
    }
    asm volatile("" ::: "memory");   // keep h-store older than out-stores

    // ---- carried out store (delta B: youngest 4 vmem ops; acks NOT drained at B1)
    int hadOut = havP;
    if (havP) {
      int c = j0 + lc;
      if (c < OUTD) {
        #pragma unroll
        for (int q = 0; q < 4; ++q) {
          int b = row0 + (w & 1) * 16 + kg * 4 + q;
          out[((long)b * 64 + colP) * OUTD + c] = faP[q] + fcb;
        }
      }
      havP = 0;
    }
    asm volatile("" ::: "memory");

    // ---- B1 drain: fc-waves with fresh outs wait vmcnt(4) (h is older -> acked);
    //      everyone else drains fully. Then tid128 publishes via the fan-in tree.
    if (hadOut) asm volatile("s_waitcnt vmcnt(4) lgkmcnt(0)" ::: "memory");
    else        asm volatile("s_waitcnt vmcnt(0) lgkmcnt(0)" ::: "memory");
    __syncthreads();
    if (tid == 128) {
      if (fast) {
        int slot = (s + 1) & 3;
        unsigned int so = atom_add_ret(gbase + 16 * (1 + (jt & 3)) + slot, 1u);
        if (so == 7u) {   // sub-group complete -> bump master
          unsigned int mo = atom_add_ret(gbase + slot, 1u);
          if (mo == 3u) { // group complete -> broadcast GO, re-zero slot s+3
            *(volatile unsigned int*)(gbase + 80 + slot) = (unsigned int)(s + 1);
            int zs = (s + 3) & 3;
            *(volatile unsigned int*)(gbase + zs) = 0u;
            *(volatile unsigned int*)(gbase + 16 + zs) = 0u;
            *(volatile unsigned int*)(gbase + 32 + zs) = 0u;
            *(volatile unsigned int*)(gbase + 48 + zs) = 0u;
            *(volatile unsigned int*)(gbase + 64 + zs) = 0u;
          }
        }
      }
      __hip_atomic_store(myflag, (unsigned int)(s + 1),   // agent channel (always)
                         __ATOMIC_RELAXED, __HIP_MEMORY_SCOPE_AGENT);
    }

    // ---- fused fc MFMA in the publish->GO shadow: result CARRIED in registers
    if (dofcW && s >= 1) {
      f32x4 fa = z;
      #pragma unroll
      for (int i = 0; i < 16; ++i) {
        bf16x8 a = *(const bf16x8*)((const char*)h_lds + (PF ^ (i << 6)));
        fa = __builtin_amdgcn_mfma_f32_16x16x32_bf16(a, Wf[i], fa, 0, 0, 0);
      }
      faP = fa; havP = 1; colP = s - 1;
    }

    // ---- wave3: passive GO wait (one read-only line), or agent fallback
    int needE = (s < LEN - 1) || (jt < 5);
    if (w == 3 && needE) {
      if (!agentMode) {
        volatile const unsigned int* gop =
            (volatile const unsigned int*)(gbase + 80 + ((s + 1) & 3));
        int spins = 0;
        for (;;) {
          asm volatile("buffer_inv\n\ts_waitcnt vmcnt(0)" ::: "memory");
          if (*gop == (unsigned int)(s + 1)) break;
          if (++spins > 1024) { agentMode = 1; break; }   // permanent demotion
          __builtin_amdgcn_s_sleep(1);
        }
      }
      if (agentMode) {
        const unsigned int* fA = flags + (mt * 32 + (lane & 31)) * 8;
        for (;;) {
          unsigned int fv = __hip_atomic_load(fA, __ATOMIC_RELAXED, __HIP_MEMORY_SCOPE_AGENT);
          if (__all((int)(fv >= (unsigned int)(s + 1)))) break;
          __builtin_amdgcn_s_sleep(1);
        }
      }
    }
    __syncthreads();   // B2: GO seen; all h_lds (h_s) reads done

    // ---- E: staging. fc-blocks: waves 2-3 stage all 32 chunks (waves 0-1 never
    //      touch vmem here -> their out acks keep draining). Others: 4-wave x 8.
    if (needE) {
      int nhalf, cb;
      if (jt < 5) { nhalf = (w >> 1) ? 2 : 0; cb = (w & 1) * 16; }
      else        { nhalf = 1; cb = w * 8; }
      if (nhalf) {
        if (fast) {   // XCD-local data (even after demotion): L1 inv suffices
          asm volatile("buffer_inv\n\ts_waitcnt vmcnt(0)" ::: "memory");
        } else {
          __builtin_amdgcn_fence(__ATOMIC_ACQUIRE, "agent");
        }
        const unsigned short* hbC = hbuf + ((s + 1) & 1) * 262144 + mt * 16384;
        for (int hf = 0; hf < nhalf; ++hf) {
          u32x4 ta[8];
          #pragma unroll
          for (int i = 0; i < 8; ++i) {
            int ci = cb + hf * 8 + i;
            ta[i] = *(const u32x4*)(hbC + ci * 512 + lane * 8);
          }
          int r_ = lane >> 1, u = lane & 1;
          #pragma unroll
          for (int i = 0; i < 8; ++i) {
            int c2 = (cb + hf * 8 + i) * 2 + u;
            *(u32x4*)(h_lds + r_ * 512 + ((c2 ^ (r_ & 7)) << 3)) = ta[i];
          }
        }
      }
    }
    __syncthreads();   // B3: h_{s+1} staged for next iteration
  }

  // epilogue: store carried out col 62, then fc on staged h_64 -> out col 63
  if (dofcW) {
    int c = j0 + lc;
    if (havP && c < OUTD) {
      #pragma unroll
      for (int q = 0; q < 4; ++q) {
        int b = row0 + (w & 1) * 16 + kg * 4 + q;
        out[((long)b * 64 + colP) * OUTD + c] = faP[q] + fcb;
      }
    }
    f32x4 fa = z;
    #pragma unroll
    for (int i = 0; i < 16; ++i) {
      bf16x8 a = *(const bf16x8*)((const char*)h_lds + (PF ^ (i << 6)));
      fa = __builtin_amdgcn_mfma_f32_16x16x32_bf16(a, Wf[i], fa, 0, 0, 0);
    }
    if (c < OUTD) {
      #pragma unroll
      for (int q = 0; q < 4; ++q) {
        int b = row0 + (w & 1) * 16 + kg * 4 + q;
        out[((long)b * 64 + 63) * OUTD + c] = fa[q] + fcb;
      }
    }
  }
}

extern "C" void kernel_launch(void* const* d_in, const int* in_sizes, int n_in,
                              void* d_out, int out_size, void* d_ws, size_t ws_size,
                              hipStream_t stream) {
  (void)in_sizes; (void)n_in; (void)out_size; (void)ws_size;
  const float* inp   = (const float*)d_in[0];
  const int*   labels= (const int*)d_in[1];
  const float* W_ih  = (const float*)d_in[3];
  const float* W_hh  = (const float*)d_in[4];
  const float* b_ih  = (const float*)d_in[5];
  const float* b_hh  = (const float*)d_in[6];
  const float* W_fc  = (const float*)d_in[7];
  const float* b_fc  = (const float*)d_in[8];
  const float* W_inh = (const float*)d_in[9];
  const float* b_inh = (const float*)d_in[10];
  const float* W_inc = (const float*)d_in[11];
  const float* b_inc = (const float*)d_in[12];

  // workspace layout (total ~8.65 MB)
  char* ws = (char*)d_ws;
  unsigned short* Weff = (unsigned short*)(ws + 0);          // 2,097,152 B (bf16 2048x512)
  float* bias_eff      = (float*)(ws + 2097152);             //     8,192 B
  unsigned short* hbuf = (unsigned short*)(ws + 2105344);    // 1,048,576 B (2 x 512 x 512 bf16, chunk layout)
  float* c0            = (float*)(ws + 3153920);             // 1,048,576 B
  float* corr0         = (float*)(ws + 4202496);             // 4,194,304 B
  float* d0            = (float*)(ws + 8396800);             //   135,168 B
  unsigned int* flags  = (unsigned int*)(ws + 8531968);      //    32,768 B (step flags + dec + xmap)
  unsigned short* Wfc16= (unsigned short*)(ws + 8564736);    //    67,584 B (bf16 66x512)
  unsigned int* flagsL = (unsigned int*)(ws + 8632320);      //    16,384 B (tree count/GO rings, XCD-local)

  k_initA<<<512, 256, 0, stream>>>(W_hh, W_ih, W_fc, b_ih, b_hh, b_fc,
                                   inp, W_inh, b_inh, W_inc, b_inc,
                                   Weff, bias_eff, hbuf, c0, Wfc16, flags, flagsL);
  k_init2a<<<512, 128, 0, stream>>>(inp, hbuf, W_fc, b_fc, d0);
  k_init2b<<<128, 256, 0, stream>>>(d0, W_ih, corr0);

  k_main<<<512, 256, 0, stream>>>(Weff, bias_eff, hbuf, c0, corr0, W_ih, labels,
                                  Wfc16, b_fc, (float*)d_out, flags, flagsL);
}

// Round 12
// 426.872 us; speedup vs baseline: 1.4858x; 1.4858x over previous
//
#include <hip/hip_runtime.h>

#define OUTD 66
#define INW  78
#define FH   2048
#define LEN  64

typedef short bf16x8 __attribute__((ext_vector_type(8)));
typedef float f32x4  __attribute__((ext_vector_type(4)));
typedef unsigned int u32x4 __attribute__((ext_vector_type(4)));

__device__ __forceinline__ float bf2f(unsigned short u) {
  union { unsigned int i; float f; } v; v.i = ((unsigned int)u) << 16; return v.f;
}
__device__ __forceinline__ unsigned short f2bf(float f) {
  union { float f; unsigned int i; } v; v.f = f;
  unsigned int u = v.i;
  return (unsigned short)((u + 0x7fffu + ((u >> 16) & 1u)) >> 16);
}
__device__ __forceinline__ float sigm(float x) { return 1.f / (1.f + __expf(-x)); }
__device__ __forceinline__ float tanh_f(float x) { return 2.f / (1.f + __expf(-2.f * x)) - 1.f; }

// Returning atomic add executed at XCD-local L2 (validated r4/r6 fast path).
__device__ __forceinline__ unsigned int atom_add_ret(unsigned int* p, unsigned int d) {
  unsigned int r;
  asm volatile("global_atomic_add %0, %1, %2, off sc0\n\ts_waitcnt vmcnt(0)"
               : "=&v"(r) : "v"(p), "v"(d) : "memory");
  return r;
}

// ---- initA (all inputs FLOAT32):
//  blocks 0..255 : Weff(bf16) = W_hh + W_ihA·W_fc fold, bias_eff(f32), zero flags/flagsL
//  blocks 256..511: h0 -> hbuf[0] (bf16, CHUNK layout), c0 (f32); block 256 converts W_fc -> Wfc16
// hbuf chunk layout: [parity][mt(16)][jt(32)][r(32)][c(16)] bf16 -> producer tile = 1KB contiguous.
__global__ __launch_bounds__(256) void k_initA(
    const float* __restrict__ W_hh, const float* __restrict__ W_ih,
    const float* __restrict__ W_fc, const float* __restrict__ b_ih,
    const float* __restrict__ b_hh, const float* __restrict__ b_fc,
    const float* __restrict__ inp, const float* __restrict__ W_inh,
    const float* __restrict__ b_inh, const float* __restrict__ W_inc,
    const float* __restrict__ b_inc,
    unsigned short* __restrict__ Weff, float* __restrict__ bias_eff,
    unsigned short* __restrict__ hbuf, float* __restrict__ c0,
    unsigned short* __restrict__ Wfc16, unsigned int* __restrict__ flags,
    unsigned int* __restrict__ flagsL)
{
  int tid = threadIdx.x, bid = blockIdx.x;
  if (bid < 256) {
    int nb = bid;
    int k = tid * 2;
    float acc[8][2];
    #pragma unroll
    for (int r = 0; r < 8; ++r) {
      int n = nb * 8 + r;
      acc[r][0] = W_hh[n * 512 + k];
      acc[r][1] = W_hh[n * 512 + k + 1];
    }
    for (int m = 0; m < OUTD; ++m) {
      float w0 = W_fc[m * 512 + k];
      float w1 = W_fc[m * 512 + k + 1];
      #pragma unroll
      for (int r = 0; r < 8; ++r) {
        float wih = W_ih[(nb * 8 + r) * INW + m];
        acc[r][0] += wih * w0;
        acc[r][1] += wih * w1;
      }
    }
    #pragma unroll
    for (int r = 0; r < 8; ++r) {
      int n = nb * 8 + r;
      unsigned int pack = (unsigned int)f2bf(acc[r][0]) | ((unsigned int)f2bf(acc[r][1]) << 16);
      *(unsigned int*)(Weff + n * 512 + k) = pack;
    }
    if (tid < 8) {
      int n = nb * 8 + tid;
      float a = b_ih[n] + b_hh[n];
      for (int m = 0; m < OUTD; ++m) a += b_fc[m] * W_ih[n * INW + m];
      bias_eff[n] = a;
    }
    if (nb == 0) {
      for (int i = tid; i < 512 * 16; i += 256) flags[i] = 0;
      for (int i = tid; i < 256 * 16; i += 256) flagsL[i] = 0;
    }
  } else {
    int nb = bid - 256;
    for (int r = 0; r < 2; ++r) {
      int b = nb * 2 + r;
      for (int half = 0; half < 2; ++half) {
        int c = tid + half * 256;
        float ha = b_inh[c], ca = b_inc[c];
        for (int m = 0; m < OUTD; ++m) {
          float f = inp[b * OUTD + m];
          ha += f * W_inh[c * OUTD + m];
          ca += f * W_inc[c * OUTD + m];
        }
        // chunk layout write: [mt=b>>5][jt=c>>4][r=b&31][c&15]
        hbuf[((b >> 5) * 32 + (c >> 4)) * 512 + (b & 31) * 16 + (c & 15)] = f2bf(ha);
        c0[b * 512 + c] = ca;
      }
    }
    if (nb == 0) {
      for (int i = tid; i < OUTD * 512; i += 256) Wfc16[i] = f2bf(W_fc[i]);
    }
  }
}

// ---- init2a: d0[b][m] = frame0 - (h0(bf16, chunk layout) @ W_fc^T + b_fc)
__global__ __launch_bounds__(128) void k_init2a(
    const float* __restrict__ inp, const unsigned short* __restrict__ hbuf,
    const float* __restrict__ W_fc, const float* __restrict__ b_fc,
    float* __restrict__ d0)
{
  int b = blockIdx.x, m = threadIdx.x;
  if (m >= OUTD) return;
  const unsigned short* hb = hbuf + (b >> 5) * 16384 + (b & 31) * 16;
  const float* wrow = W_fc + m * 512;
  float acc = 0.f;
  for (int k = 0; k < 512; ++k)
    acc += bf2f(hb[(k >> 4) * 512 + (k & 15)]) * wrow[k];
  d0[b * OUTD + m] = inp[b * OUTD + m] - (acc + b_fc[m]);
}

// ---- init2b: corr0[b][n] = d0[b] @ W_ihA[n]^T
__global__ __launch_bounds__(256) void k_init2b(
    const float* __restrict__ d0, const float* __restrict__ W_ih,
    float* __restrict__ corr0)
{
  __shared__ float ds[4][OUTD];
  int tid = threadIdx.x, b0 = blockIdx.x * 4;
  for (int i = tid; i < 4 * OUTD; i += 256) ds[i / OUTD][i % OUTD] = d0[b0 * OUTD + i];
  __syncthreads();
  for (int n = tid; n < FH; n += 256) {
    float a0 = 0, a1 = 0, a2 = 0, a3 = 0;
    const float* wr = W_ih + n * INW;
    for (int m = 0; m < OUTD; ++m) {
      float w = wr[m];
      a0 += ds[0][m] * w; a1 += ds[1][m] * w; a2 += ds[2][m] * w; a3 += ds[3][m] * w;
    }
    corr0[(b0 + 0) * FH + n] = a0;
    corr0[(b0 + 1) * FH + n] = a1;
    corr0[(b0 + 2) * FH + n] = a2;
    corr0[(b0 + 3) * FH + n] = a3;
  }
}

// ---- main persistent LSTM kernel (CHAMPION r6, restored verbatim).
// 512 blocks (mt 16 x jt 32), 32 rows x 16 hcols, 32KB LDS, 2 blocks/CU.
// Handshake v4 (single-writer GO broadcast): producers each do ONE returning
// atom_add (sc0, XCD-local L2) on a per-(group,step) count word; the 32nd writes a
// single GO word (plain store -> local L2). Only wave3 polls that ONE read-only
// line (buffer_inv + plain load); barrier releases the block; then one inv +
// unconditional fully-coalesced batch load of all 32 chunks (GO guarantees
// completeness). Ring-of-4 slots, monotone GO values; count slot re-zeroed 2 steps
// ahead by the GO-writer. fc MFMA runs in the publish->GO shadow with the result
// CARRIED in registers; the out store issues at the next loop top so its HBM ack
// retires under the GEMM before B1's drain. Bounded spins -> permanent demotion to
// the always-dual-published agent flags (hang-proof).
// Winning mechanism (r2..r11 matrix): PASSIVE wait + co-residency. Active polling,
// 1/CU, fan-in trees, swizzle-16, store-in-shadow all measured worse.
__global__ __launch_bounds__(256, 2) void k_main(
    const unsigned short* __restrict__ Weff, const float* __restrict__ bias_eff,
    unsigned short* __restrict__ hbuf, const float* __restrict__ c0,
    const float* __restrict__ corr0, const float* __restrict__ W_ih,
    const int* __restrict__ labels, const unsigned short* __restrict__ Wfc16,
    const float* __restrict__ b_fc, float* __restrict__ out,
    unsigned int* __restrict__ flags, unsigned int* __restrict__ flagsL)
{
  __shared__ __align__(16) unsigned short h_lds[32 * 512];  // 32768 B, XOR-swizzled 16B granules

  int tid = threadIdx.x, bid = blockIdx.x;
  int w = tid >> 6, lane = tid & 63;
  int lc = lane & 15, kg = lane >> 4;
  // flags word layout: [0,4096) step flags (512 producers x stride 8)
  //                    4100 decision word ; [4608, 6656) xmap (512 x stride 4)
  unsigned int* xmap = flags + 4608;
  unsigned int* decp = flags + 4100;
  // flagsL: per-group 256B region: [mt*64 + 0..3] count ring, [mt*64 + 32..35] GO ring

  // ---- publish my XCC_ID (gfx950-verified: learn_hip m09)
  unsigned int xcd;
  asm volatile("s_getreg_b32 %0, hwreg(HW_REG_XCC_ID)" : "=s"(xcd));
  if (tid == 0)
    __hip_atomic_store(&xmap[bid * 4], xcd + 1u, __ATOMIC_RELAXED, __HIP_MEMORY_SCOPE_AGENT);

  // ---- leader (block 0, wave 0) verifies both candidate layouts, publishes decision
  if (bid == 0 && w == 0) {
    int okA = 1, okB = 1;
    #pragma unroll
    for (int i = 0; i < 8; ++i) {
      int b = lane + i * 64;
      unsigned int v, ra, rb;
      const unsigned int* xp = &xmap[b * 4];
      for (;;) { v = __hip_atomic_load(xp, __ATOMIC_RELAXED, __HIP_MEMORY_SCOPE_AGENT);
                 if (v) break; __builtin_amdgcn_s_sleep(1); }
      const unsigned int* pa = &xmap[(b & 15) * 4];
      for (;;) { ra = __hip_atomic_load(pa, __ATOMIC_RELAXED, __HIP_MEMORY_SCOPE_AGENT);
                 if (ra) break; __builtin_amdgcn_s_sleep(1); }
      const unsigned int* pb = &xmap[((b >> 5) << 5) * 4];
      for (;;) { rb = __hip_atomic_load(pb, __ATOMIC_RELAXED, __HIP_MEMORY_SCOPE_AGENT);
                 if (rb) break; __builtin_amdgcn_s_sleep(1); }
      okA &= (v == ra); okB &= (v == rb);
    }
    okA = __all(okA); okB = __all(okB);
    if (lane == 0) {
      unsigned int d = okA ? 1u : (okB ? 2u : 3u);
      __hip_atomic_store(decp, d, __ATOMIC_RELAXED, __HIP_MEMORY_SCOPE_AGENT);
    }
  }
  if (tid == 0) {
    unsigned int dd;
    for (;;) { dd = __hip_atomic_load(decp, __ATOMIC_RELAXED, __HIP_MEMORY_SCOPE_AGENT);
               if (dd) break; __builtin_amdgcn_s_sleep(1); }
    h_lds[0] = (unsigned short)dd;
  }
  __syncthreads();
  unsigned int dmode = h_lds[0];
  __syncthreads();

  int fast, mt, jt;
  if (dmode == 1u)      { fast = 1; mt = bid & 15;  jt = bid >> 4; }
  else if (dmode == 2u) { fast = 1; mt = bid >> 5;  jt = bid & 31; }
  else                  { fast = 0; mt = bid & 15;  jt = bid >> 4; }

  int row0 = mt * 32, j0 = jt * 16;
  int hx0 = (w >> 1) * 8;
  int xloc = lc & 7;
  int G = lc >> 3;                       // 0: holds gates i,g ; 1: holds f,o
  int hcol = j0 + hx0 + xloc;            // global hidden col this lane activates
  int rw0 = (w & 1) * 16;                // wave-local row base (rows 0..31)

  // LDS swizzle precompute (addr_i = P ^ (i<<6)); period-8 (r6-proven)
  int sA = xloc;
  int tA16 = ((kg ^ sA) & 3) << 4;
  int ue64 = ((sA >> 2) & 1) << 6;
  int PA0 = (rw0 + lc) * 1024 + tA16 + ue64;
  int PF  = ((w & 1) * 16 + lc) * 1024 + tA16 + ue64;   // fc rows, waves 0..1 only

  // ---- Weff B fragments (step-invariant)
  bf16x8 Bfrag[16][2];
  #pragma unroll
  for (int cg = 0; cg < 2; ++cg) {
    int n = (cg * 2 + G) * 512 + hcol;
    const unsigned short* p = Weff + n * 512 + kg * 8;
    #pragma unroll
    for (int i = 0; i < 16; ++i) Bfrag[i][cg] = *(const bf16x8*)(p + i * 32);
  }

  // ---- W_fc B fragments for fused fc (waves 0..1; jt<5 covers out cols 0..79)
  bf16x8 Wf[16];
  float fcb = 0.f;
  int dofcW = (jt < 5) & (w < 2);
  {
    int n = j0 + lc;
    if (dofcW && n < OUTD) {
      const unsigned short* p = Wfc16 + n * 512 + kg * 8;
      #pragma unroll
      for (int i = 0; i < 16; ++i) Wf[i] = *(const bf16x8*)(p + i * 32);
      fcb = b_fc[n];
    } else {
      bf16x8 z8 = {0, 0, 0, 0, 0, 0, 0, 0};
      #pragma unroll
      for (int i = 0; i < 16; ++i) Wf[i] = z8;
    }
  }

  // ---- activation constants (2 h values per lane: rows rw0+kg*4+qsel+{0,1})
  int qsel = G * 2;
  float lt[4][2], creg[2];
  #pragma unroll
  for (int idx = 0; idx < 2; ++idx) {
    int rloc = rw0 + kg * 4 + qsel + idx;
    int grow = row0 + rloc;
    int lab = labels[grow];
    #pragma unroll
    for (int gt = 0; gt < 4; ++gt) {
      int n = gt * 512 + hcol;
      lt[gt][idx] = bias_eff[n] + W_ih[n * INW + OUTD + lab];
    }
    creg[idx] = c0[grow * 512 + hcol];
  }

  const f32x4 z = {0.f, 0.f, 0.f, 0.f};
  unsigned int* myflag = &flags[(mt * 32 + jt) * 8];
  int agentMode = !fast;   // wave3 demotion is permanent

  // ---- prologue: stage h_0 (parity 0, chunk layout, contiguous) into LDS
  {
    const unsigned short* hsrc = hbuf + mt * 16384;
    #pragma unroll
    for (int i = 0; i < 8; ++i) {
      int n = tid + i * 256;              // 16B piece index 0..2047
      int c = n >> 6, q = n & 63;
      int r = q >> 1, u = q & 1, g = c * 2 + u;
      *(u32x4*)(h_lds + r * 512 + ((g ^ (r & 7)) << 3)) =
          *(const u32x4*)(hsrc + n * 8);
    }
  }
  __syncthreads();

  f32x4 faP = z; int havP = 0, colP = 0;

  for (int s = 0; s < LEN; ++s) {
    // ---- carried out store (issued at loop top: ~2us of GEMM before B1's drain)
    if (havP) {
      int c = j0 + lc;
      if (c < OUTD) {
        #pragma unroll
        for (int q = 0; q < 4; ++q) {
          int b = row0 + (w & 1) * 16 + kg * 4 + q;
          out[((long)b * 64 + colP) * OUTD + c] = faP[q] + fcb;
        }
      }
      havP = 0;
    }

    // ---- A: gates = h_s @ Weff (h_s in LDS)
    f32x4 acc00 = z, acc01 = z;
    #pragma unroll
    for (int i = 0; i < 16; ++i) {
      bf16x8 a0 = *(const bf16x8*)((const char*)h_lds + (PA0 ^ (i << 6)));
      acc00 = __builtin_amdgcn_mfma_f32_16x16x32_bf16(a0, Bfrag[i][0], acc00, 0, 0, 0);
      acc01 = __builtin_amdgcn_mfma_f32_16x16x32_bf16(a0, Bfrag[i][1], acc01, 0, 0, 0);
    }

    // exchange missing gates with partner lane (lane^8)
    f32x4 sh00, sh01;
    #pragma unroll
    for (int j = 0; j < 4; ++j) {
      sh00[j] = __shfl_xor(acc00[j], 8);
      sh01[j] = __shfl_xor(acc01[j], 8);
    }

    // activation (2 values per lane)
    unsigned short hval[2];
    #pragma unroll
    for (int idx = 0; idx < 2; ++idx) {
      int qo = qsel + idx;
      float xi = (G ? sh00[qo] : acc00[qo]);
      float xf = (G ? acc00[qo] : sh00[qo]);
      float xg = (G ? sh01[qo] : acc01[qo]);
      float xo = (G ? acc01[qo] : sh01[qo]);
      xi += lt[0][idx]; xf += lt[1][idx]; xg += lt[2][idx]; xo += lt[3][idx];
      if (s == 0) {
        int rloc = rw0 + kg * 4 + qo;
        const float* cr = corr0 + (long)(row0 + rloc) * FH + hcol;
        xi += cr[0]; xf += cr[512]; xg += cr[1024]; xo += cr[1536];
      }
      float cn = sigm(xf) * creg[idx] + sigm(xi) * tanh_f(xg);
      creg[idx] = cn;
      hval[idx] = f2bf(sigm(xo) * tanh_f(cn));
    }

    // ---- store h_{s+1} (opposite parity, CHUNK layout: our tile is contiguous 1KB)
    {
      unsigned int* hdst32 = (unsigned int*)(hbuf + ((s + 1) & 1) * 262144);
      int base32 = (mt * 32 + jt) * 256;
      int ceL = (hx0 >> 1) + (xloc >> 1);    // local col-pair 0..7
      int odd = xloc & 1;
      unsigned int pkS = 0; int rlS = 0;
      #pragma unroll
      for (int idx = 0; idx < 2; ++idx) {
        unsigned int mine = hval[idx];
        unsigned int part = (unsigned int)__shfl_xor((int)mine, 1);
        unsigned int p = odd ? (part | (mine << 16)) : (mine | (part << 16));
        if (idx == odd) { pkS = p; rlS = rw0 + kg * 4 + qsel + idx; }
      }
      if (fast) {
        hdst32[base32 + rlS * 8 + ceL] = pkS;
      } else {
        __hip_atomic_store(&hdst32[base32 + rlS * 8 + ceL], pkS,
                           __ATOMIC_RELAXED, __HIP_MEMORY_SCOPE_AGENT);
      }
    }

    // ---- B1: drain all stores (h + carried out), then tid128 publishes count/GO
    __builtin_amdgcn_s_waitcnt(0);
    __syncthreads();
    if (tid == 128) {   // wave2 lane0
      if (fast) {
        unsigned int* cntp = &flagsL[mt * 64 + ((s + 1) & 3)];
        unsigned int old = atom_add_ret(cntp, 1u);
        if (old == 31u) {   // last producer: broadcast GO, re-zero slot s+3
          *(volatile unsigned int*)&flagsL[mt * 64 + 32 + ((s + 1) & 3)] =
              (unsigned int)(s + 1);
          *(volatile unsigned int*)&flagsL[mt * 64 + ((s + 3) & 3)] = 0u;
        }
      }
      __hip_atomic_store(myflag, (unsigned int)(s + 1),   // agent channel (always)
                         __ATOMIC_RELAXED, __HIP_MEMORY_SCOPE_AGENT);
    }

    // ---- fused fc MFMA in the publish->GO shadow: result CARRIED in registers
    if (dofcW && s >= 1) {
      f32x4 fa = z;
      #pragma unroll
      for (int i = 0; i < 16; ++i) {
        bf16x8 a = *(const bf16x8*)((const char*)h_lds + (PF ^ (i << 6)));
        fa = __builtin_amdgcn_mfma_f32_16x16x32_bf16(a, Wf[i], fa, 0, 0, 0);
      }
      faP = fa; havP = 1; colP = s - 1;
    }

    // ---- wave3: passive GO wait (one read-only line), or agent fallback
    int needE = (s < LEN - 1) || (jt < 5);
    if (w == 3 && needE) {
      if (!agentMode) {
        volatile const unsigned int* gop =
            (volatile const unsigned int*)&flagsL[mt * 64 + 32 + ((s + 1) & 3)];
        int spins = 0;
        for (;;) {
          asm volatile("buffer_inv\n\ts_waitcnt vmcnt(0)" ::: "memory");
          if (*gop == (unsigned int)(s + 1)) break;
          if (++spins > 1024) { agentMode = 1; break; }   // permanent demotion
          __builtin_amdgcn_s_sleep(1);
        }
      }
      if (agentMode) {
        const unsigned int* fA = flags + (mt * 32 + (lane & 31)) * 8;
        for (;;) {
          unsigned int fv = __hip_atomic_load(fA, __ATOMIC_RELAXED, __HIP_MEMORY_SCOPE_AGENT);
          if (__all((int)(fv >= (unsigned int)(s + 1)))) break;
          __builtin_amdgcn_s_sleep(1);
        }
      }
    }
    __syncthreads();   // B2: GO seen; all h_lds (h_s) reads done

    // ---- E: freshness + unconditional fully-coalesced batch stage of h_{s+1}
    if (needE) {
      if (fast) {   // XCD-local data (even after demotion): L1 inv suffices
        asm volatile("buffer_inv\n\ts_waitcnt vmcnt(0)" ::: "memory");
      } else {
        __builtin_amdgcn_fence(__ATOMIC_ACQUIRE, "agent");
      }
      const unsigned short* hbC = hbuf + ((s + 1) & 1) * 262144 + mt * 16384;
      u32x4 ta[8];
      #pragma unroll
      for (int i = 0; i < 8; ++i) {
        const unsigned short* cp = hbC + (w * 8 + i) * 512 + lane * 8;
        ta[i] = *(const u32x4*)cp;
      }
      int r_ = lane >> 1, u = lane & 1;
      #pragma unroll
      for (int i = 0; i < 8; ++i) {
        int c2 = (w * 8 + i) * 2 + u;
        *(u32x4*)(h_lds + r_ * 512 + ((c2 ^ (r_ & 7)) << 3)) = ta[i];
      }
    }
    __syncthreads();   // B3: h_{s+1} staged for next iteration
  }

  // epilogue: store carried out col 62, then fc on staged h_64 -> out col 63
  if (dofcW) {
    int c = j0 + lc;
    if (havP && c < OUTD) {
      #pragma unroll
      for (int q = 0; q < 4; ++q) {
        int b = row0 + (w & 1) * 16 + kg * 4 + q;
        out[((long)b * 64 + colP) * OUTD + c] = faP[q] + fcb;
      }
    }
    f32x4 fa = z;
    #pragma unroll
    for (int i = 0; i < 16; ++i) {
      bf16x8 a = *(const bf16x8*)((const char*)h_lds + (PF ^ (i << 6)));
      fa = __builtin_amdgcn_mfma_f32_16x16x32_bf16(a, Wf[i], fa, 0, 0, 0);
    }
    if (c < OUTD) {
      #pragma unroll
      for (int q = 0; q < 4; ++q) {
        int b = row0 + (w & 1) * 16 + kg * 4 + q;
        out[((long)b * 64 + 63) * OUTD + c] = fa[q] + fcb;
      }
    }
  }
}

extern "C" void kernel_launch(void* const* d_in, const int* in_sizes, int n_in,
                              void* d_out, int out_size, void* d_ws, size_t ws_size,
                              hipStream_t stream) {
  (void)in_sizes; (void)n_in; (void)out_size; (void)ws_size;
  const float* inp   = (const float*)d_in[0];
  const int*   labels= (const int*)d_in[1];
  const float* W_ih  = (const float*)d_in[3];
  const float* W_hh  = (const float*)d_in[4];
  const float* b_ih  = (const float*)d_in[5];
  const float* b_hh  = (const float*)d_in[6];
  const float* W_fc  = (const float*)d_in[7];
  const float* b_fc  = (const float*)d_in[8];
  const float* W_inh = (const float*)d_in[9];
  const float* b_inh = (const float*)d_in[10];
  const float* W_inc = (const float*)d_in[11];
  const float* b_inc = (const float*)d_in[12];

  // workspace layout (total ~8.65 MB)
  char* ws = (char*)d_ws;
  unsigned short* Weff = (unsigned short*)(ws + 0);          // 2,097,152 B (bf16 2048x512)
  float* bias_eff      = (float*)(ws + 2097152);             //     8,192 B
  unsigned short* hbuf = (unsigned short*)(ws + 2105344);    // 1,048,576 B (2 x 512 x 512 bf16, chunk layout)
  float* c0            = (float*)(ws + 3153920);             // 1,048,576 B
  float* corr0         = (float*)(ws + 4202496);             // 4,194,304 B
  float* d0            = (float*)(ws + 8396800);             //   135,168 B
  unsigned int* flags  = (unsigned int*)(ws + 8531968);      //    32,768 B (step flags + dec + xmap)
  unsigned short* Wfc16= (unsigned short*)(ws + 8564736);    //    67,584 B (bf16 66x512)
  unsigned int* flagsL = (unsigned int*)(ws + 8632320);      //    16,384 B (count/GO rings, XCD-local)

  k_initA<<<512, 256, 0, stream>>>(W_hh, W_ih, W_fc, b_ih, b_hh, b_fc,
                                   inp, W_inh, b_inh, W_inc, b_inc,
                                   Weff, bias_eff, hbuf, c0, Wfc16, flags, flagsL);
  k_init2a<<<512, 128, 0, stream>>>(inp, hbuf, W_fc, b_fc, d0);
  k_init2b<<<128, 256, 0, stream>>>(d0, W_ih, corr0);

  k_main<<<512, 256, 0, stream>>>(Weff, bias_eff, hbuf, c0, corr0, W_ih, labels,
                                  Wfc16, b_fc, (float*)d_out, flags, flagsL);
}